// Round 18
// baseline (700.598 us; speedup 1.0000x reference)
//
#include <hip/hip_runtime.h>

// Axial attention for N=16, C=64, H=W=256.
// hT = d_ws[0..128MB):   (N,H,W,C) bf16 pixels (128B each)
// O' = d_ws[128..256MB): (N,W,H,C) bf16  [w-major: attn<0> writes contiguous slices]
//
// K1 transpose_kernel: h (NCHW f32) -> hT (N,H,W,C bf16)
// K2 attn<0> (row):  per (n,w): X = hT[:, :, w, :]; O' = out_r + bv + X (full slice)
// K3 attn<1> (col):  per (n,y): X = hT[n][y] (contig); O' staged via LDS;
//                    out = out_c + bv + O' (fp32 NCHW, coalesced)
//
// softmax(q.k^T) == softmax( X*(At/16)*X^T + w[g]/16 ), At^T = Wk^T Wq as A-operand;
// w[g] = X[g].(Wk^T bq); query-bias terms cancel; bk cancels. V bias in epilogue.
// No max-sub (scores bounded, fp32 exp safe); log2e folded into At/w16s.
//
// R18 = R16 (377us best structure: 8 waves, 2 q-tiles/wave, shared kt reads)
// + micro: (1) w16s computed by all 512 threads (tid pairs split the 64-term
// dot, shfl_xor(1) combine) - halves its serial FMA chain; (2) depth-1 software
// pipeline in the kt loop: xa/cw of kt+1 issued before kt's PV MFMAs.

typedef unsigned short u16t;
typedef __bf16 bf16x8 __attribute__((ext_vector_type(8)));
typedef __bf16 bf16x2 __attribute__((ext_vector_type(2)));
typedef float  f32x4  __attribute__((ext_vector_type(4)));
typedef u16t   us8    __attribute__((ext_vector_type(8)));
typedef u16t   us4    __attribute__((ext_vector_type(4)));
typedef unsigned uu4  __attribute__((ext_vector_type(4)));

#define DEVINL __device__ __forceinline__

#define SCL16 0.09016844f   // log2(e)/16

DEVINL u16t f2bf(float f){
    return __builtin_bit_cast(u16t, (__bf16)f);      // hw cvt (RNE)
}
DEVINL float bf2f(u16t h){
    unsigned u = ((unsigned)h) << 16;
    return __builtin_bit_cast(float, u);
}
DEVINL unsigned pk2(float lo, float hi){
    bf16x2 t; t[0] = (__bf16)lo; t[1] = (__bf16)hi;  // canonical v_cvt_pk pattern
    return __builtin_bit_cast(unsigned, t);
}
DEVINL f32x4 mfma16(bf16x8 a, bf16x8 b, f32x4 c){
    return __builtin_amdgcn_mfma_f32_16x16x32_bf16(a, b, c, 0, 0, 0);
}
// Xs swizzle (reference form; hot loops use hoisted equivalents)
DEVINL int xswz(int row, int chunk){
    return row*128 + ((chunk << 4) ^ (((row & 7) ^ ((row >> 2) & 7)) << 4));
}

// ---------------- K1: transpose h (N,C,H,W) f32 -> hT (N,H,W,C) bf16 ----------------
__global__ __launch_bounds__(256) void transpose_kernel(const float* __restrict__ h,
                                                        u16t* __restrict__ hT){
    __shared__ float tile[64][257];
    const int bid = blockIdx.x;          // n*256 + y
    const int n = bid >> 8, y = bid & 255;
    const int tid = threadIdx.x;
    {
        const int c = tid >> 2, w0 = (tid & 3) * 64;
        const int base = ((n * 64 + c) * 256 + y) * 256 + w0;
        #pragma unroll
        for (int i = 0; i < 16; ++i){
            f32x4 v = *(const f32x4*)(h + base + i * 4);
            tile[c][w0 + i*4 + 0] = v[0];
            tile[c][w0 + i*4 + 1] = v[1];
            tile[c][w0 + i*4 + 2] = v[2];
            tile[c][w0 + i*4 + 3] = v[3];
        }
    }
    __syncthreads();
    #pragma unroll
    for (int j = 0; j < 4; ++j){
        const int task = tid + 256 * j;
        const int w = task >> 2, c0 = (task & 3) * 16;
        us8 o0, o1;
        #pragma unroll
        for (int e = 0; e < 8; ++e) o0[e] = f2bf(tile[c0 + e][w]);
        #pragma unroll
        for (int e = 0; e < 8; ++e) o1[e] = f2bf(tile[c0 + 8 + e][w]);
        const int ob = ((n * 256 + y) * 256 + w) * 64 + c0;
        *(us8*)(hT + ob)     = o0;
        *(us8*)(hT + ob + 8) = o1;
    }
}

// ---------------- K2/K3: attention (full-slice blocks, 2 q-tiles per wave) ----------------
template<int COL>
__global__ __launch_bounds__(512, 4) void attn_kernel(
    const u16t* __restrict__ Xg,
    const float* __restrict__ wq, const float* __restrict__ bq,
    const float* __restrict__ wk, const float* __restrict__ wvw,
    const float* __restrict__ bvp,
    u16t* __restrict__ Og,
    float* __restrict__ outp)
{
    __shared__ __align__(16) u16t Xs[16384];    // X 256x64 bf16 swizzled; COL: later O' stage
    __shared__ __align__(16) u16t VtF[16384];   // V as PV B-frags (linear); reused as OutS
    __shared__ __align__(16) u16t AtF[4096];    // At^T*log2e/16 as A-frags (virtual perm)
    __shared__ __align__(16) float w16s[256];
    __shared__ float wkbqs[64];
    __shared__ float bvs[64];

    const int tid  = threadIdx.x;
    const int lane = tid & 63;
    const int wv   = tid >> 6;                 // wave 0..7
    const int bid  = blockIdx.x;               // grid = 4096
    const int n    = bid >> 8;
    const int idx  = bid & 255;                // w (row mode) or y (col mode)
    const int l15  = lane & 15;
    const int l4   = lane >> 4;
    const int nbase = n * 4194304;
    const int sbase = nbase + idx * 16384;
    const int aa   = l15 >> 2, bb = l15 & 3;
    const char* Xc = (const char*)Xs;

    // ---- phase 0a: stage full X into LDS (hoisted pass-invariant swizzle)
    {
        const int r0 = tid >> 3, cc = tid & 7;
        const int swzS = (((r0 & 7) ^ ((tid >> 5) & 7)) << 4);
        char* pdst = (char*)Xs + r0*128 + ((cc << 4) ^ swzS);
        const u16t* psrc = Xg + (COL ? (sbase + r0*64 + cc*8)
                                     : (nbase + r0*16384 + idx*64 + cc*8));
        const int gstep = COL ? 4096 : 1048576;   // 64 rows per pass
        #pragma unroll
        for (int pass = 0; pass < 4; ++pass){
            us8 v = *(const us8*)(psrc + pass*gstep);
            *(us8*)(pdst + pass*8192) = v;
        }
    }

    // ---- phase 0b: At^T*log2e/16 -> AtF (A-frag layout, virtual-row perm)
    {
        const int mtA = wv >> 1;
        us8 aku[2];
        #pragma unroll
        for (int kt = 0; kt < 2; ++kt)
            #pragma unroll
            for (int e = 0; e < 8; ++e)
                aku[kt][e] = f2bf(wk[(kt*32 + l4*8 + e)*64 + mtA*16 + l15]);
        #pragma unroll
        for (int t2 = 0; t2 < 2; ++t2){
            const int ntA = (2*wv + t2) & 3;
            us8 bqu[2];
            #pragma unroll
            for (int kt = 0; kt < 2; ++kt)
                #pragma unroll
                for (int e = 0; e < 8; ++e)
                    bqu[kt][e] = f2bf(wq[(kt*32 + l4*8 + e)*64 + ntA*16 + l15]);
            f32x4 acc = {0.f,0.f,0.f,0.f};
            acc = mfma16(__builtin_bit_cast(bf16x8, aku[0]), __builtin_bit_cast(bf16x8, bqu[0]), acc);
            acc = mfma16(__builtin_bit_cast(bf16x8, aku[1]), __builtin_bit_cast(bf16x8, bqu[1]), acc);
            #pragma unroll
            for (int r = 0; r < 4; ++r){
                const int cp = mtA*16 + 4*l4 + r;          // row of At^T (= c')
                const int cc = ntA*16 + l15;               // col (= c, the k-dim)
                const int vtq  = 2*(cp>>5) + ((cp>>2)&1);
                const int mrow = 4*((cp>>3)&3) + (cp&3);
                const int f    = vtq*2 + (cc>>5);
                AtF[(f*64 + ((cc>>3)&3)*16 + mrow)*8 + (cc&7)] = f2bf(acc[r] * SCL16);
            }
        }
    }
    if (tid < 64){
        float acc = 0.f;
        for (int o = 0; o < 64; ++o) acc += wk[o*64 + tid] * bq[o];
        wkbqs[tid] = acc;
        bvs[tid] = bvp[tid];
    }
    __syncthreads();

    // ---- phase 1: V = X @ Wv^T -> PV B-frag layout (hoisted addresses)
    {
        const int ct = wv >> 1;
        bf16x8 awv[2];
        #pragma unroll
        for (int ktc = 0; ktc < 2; ++ktc){
            const float* wp = wvw + (ct*16 + l15)*64 + ktc*32 + l4*8;
            f32x4 v0 = *(const f32x4*)wp;
            f32x4 v1 = *(const f32x4*)(wp + 4);
            us8 u;
            #pragma unroll
            for (int e = 0; e < 4; ++e){ u[e] = f2bf(v0[e]); u[4+e] = f2bf(v1[e]); }
            awv[ktc] = __builtin_bit_cast(bf16x8, u);
        }
        // read bases: row = gt*16 + l15, gt = (wv&1)*8 + t; parity constants
        const char* pb0 = Xc + (wv&1)*16384 + l15*128;
        const int swzE = (((l15&7) ^ aa) << 4);
        const int swzO = (((l15&7) ^ (4+aa)) << 4);
        const int cE0 = (l4<<4) ^ swzE, cE1 = ((4+l4)<<4) ^ swzE;
        const int cO0 = (l4<<4) ^ swzO, cO1 = ((4+l4)<<4) ^ swzO;
        // write base: VtF[(fidx*64 + lt + rr)*8 + e] bytes
        char* pvw = (char*)VtF + (ct*8 + (wv&1)*4)*1024 + (l15>>3)*256 + l4*64 + (l15&7)*2;
        #pragma unroll
        for (int t = 0; t < 8; ++t){
            const int o0 = (t&1) ? cO0 : cE0, o1 = (t&1) ? cO1 : cE1;
            bf16x8 bx0 = *(const bf16x8*)(pb0 + t*2048 + o0);
            bf16x8 bx1 = *(const bf16x8*)(pb0 + t*2048 + o1);
            f32x4 z = {0.f,0.f,0.f,0.f};
            z = mfma16(awv[0], bx0, z);
            z = mfma16(awv[1], bx1, z);
            char* pw8 = pvw + (t>>1)*1024 + (t&1)*512;
            #pragma unroll
            for (int rr = 0; rr < 4; ++rr)
                *(u16t*)(pw8 + rr*16) = f2bf(z[rr]);
        }
    }
    {
        // w16s on ALL 512 threads: pair (tid, tid^1) splits the 64-term dot.
        const int row = tid >> 1;
        const int cbase = (tid & 1) * 4;
        float acc = 0.f;
        #pragma unroll
        for (int cc = 0; cc < 4; ++cc){
            us8 xv = *(const us8*)(Xc + xswz(row, cbase + cc));
            #pragma unroll
            for (int e = 0; e < 8; ++e) acc += bf2f(xv[e]) * wkbqs[(cbase + cc)*8 + e];
        }
        acc += __shfl_xor(acc, 1);
        if (!(tid & 1)) w16s[row] = acc * SCL16;
    }
    __syncthreads();

    // ---- phase 2: TWO q-tiles per wave (mt = wv, wv+8), flash-fused, reads shared,
    //      depth-1 software pipeline on xa/cw.
    const int rowoff = 8*aa + bb;

    // q~ for both tiles; AtF frags read once, shared across mi
    const char* pat = (const char*)AtF + lane*16;
    bf16x8 xq[2][2];
    #pragma unroll
    for (int mi = 0; mi < 2; ++mi){
        const int mt = wv + 8*mi;
        xq[mi][0] = *(const bf16x8*)(Xc + xswz(mt*16 + l15, l4));
        xq[mi][1] = *(const bf16x8*)(Xc + xswz(mt*16 + l15, 4 + l4));
    }
    uu4 qp[2][2];
    #pragma unroll
    for (int vtq = 0; vtq < 4; ++vtq){
        bf16x8 a0 = *(const bf16x8*)(pat + (vtq*2 + 0)*1024);
        bf16x8 a1 = *(const bf16x8*)(pat + (vtq*2 + 1)*1024);
        #pragma unroll
        for (int mi = 0; mi < 2; ++mi){
            f32x4 z = {0.f,0.f,0.f,0.f};
            z = mfma16(a0, xq[mi][0], z);
            z = mfma16(a1, xq[mi][1], z);
            qp[mi][vtq>>1][(vtq&1)*2 + 0] = pk2(z[0], z[1]);
            qp[mi][vtq>>1][(vtq&1)*2 + 1] = pk2(z[2], z[3]);
        }
    }
    bf16x8 qb[2][2];
    qb[0][0] = __builtin_bit_cast(bf16x8, qp[0][0]);
    qb[0][1] = __builtin_bit_cast(bf16x8, qp[0][1]);
    qb[1][0] = __builtin_bit_cast(bf16x8, qp[1][0]);
    qb[1][1] = __builtin_bit_cast(bf16x8, qp[1][1]);

    // hoisted virtual-read bases: row = 32kt + 4sub + rowoff (disjoint bitfields)
    const int swz0 = (bb ^ (2*aa)) << 4;
    const int swz1 = ((4 + bb) ^ ((2*aa + 1) & 7)) << 4;
    const char* pv00 = Xc + rowoff*128 + ((l4<<4) ^ swz0);
    const char* pv01 = Xc + rowoff*128 + (((4+l4)<<4) ^ swz0);
    const char* pv10 = Xc + rowoff*128 + 512 + ((l4<<4) ^ swz1);
    const char* pv11 = Xc + rowoff*128 + 512 + (((4+l4)<<4) ^ swz1);
    const char* pvv = (const char*)VtF + lane*16;   // linear, conflict-free
    const char* pw  = (const char*)w16s + l4*32;

    // ones B-frag for row-sum MFMA
    uu4 onep; onep[0] = 0x3F803F80u; onep[1] = 0x3F803F80u; onep[2] = 0x3F803F80u; onep[3] = 0x3F803F80u;
    const bf16x8 onesb = __builtin_bit_cast(bf16x8, onep);

    f32x4 po[2][4] = {{{0.f,0.f,0.f,0.f},{0.f,0.f,0.f,0.f},{0.f,0.f,0.f,0.f},{0.f,0.f,0.f,0.f}},
                      {{0.f,0.f,0.f,0.f},{0.f,0.f,0.f,0.f},{0.f,0.f,0.f,0.f},{0.f,0.f,0.f,0.f}}};
    f32x4 po_sum[2] = {{0.f,0.f,0.f,0.f},{0.f,0.f,0.f,0.f}};

    // software pipeline: xa/cw of kt+1 in flight during kt's exp/PV
    bf16x8 nxa00 = *(const bf16x8*)(pv00);
    bf16x8 nxa01 = *(const bf16x8*)(pv01);
    bf16x8 nxa10 = *(const bf16x8*)(pv10);
    bf16x8 nxa11 = *(const bf16x8*)(pv11);
    f32x4  ncw0  = *(const f32x4*)(pw);
    f32x4  ncw1  = *(const f32x4*)(pw + 16);

    #pragma unroll
    for (int kt = 0; kt < 8; ++kt){
        bf16x8 xa00 = nxa00, xa01 = nxa01, xa10 = nxa10, xa11 = nxa11;
        f32x4 cw0 = ncw0, cw1 = ncw1;
        bf16x8 vb[4];
        #pragma unroll
        for (int nt = 0; nt < 4; ++nt)
            vb[nt] = *(const bf16x8*)(pvv + (nt*8 + kt)*1024);
        if (kt < 7){
            nxa00 = *(const bf16x8*)(pv00 + (kt+1)*4096);
            nxa01 = *(const bf16x8*)(pv01 + (kt+1)*4096);
            nxa10 = *(const bf16x8*)(pv10 + (kt+1)*4096);
            nxa11 = *(const bf16x8*)(pv11 + (kt+1)*4096);
            ncw0  = *(const f32x4*)(pw + (kt+1)*128);
            ncw1  = *(const f32x4*)(pw + (kt+1)*128 + 16);
        }

        __builtin_amdgcn_s_setprio(1);
        bf16x8 pa[2];
        #pragma unroll
        for (int mi = 0; mi < 2; ++mi){
            uu4 tt;
            f32x4 z0 = cw0;
            z0 = mfma16(xa00, qb[mi][0], z0);
            z0 = mfma16(xa01, qb[mi][1], z0);
            tt[0] = pk2(__builtin_amdgcn_exp2f(z0[0]), __builtin_amdgcn_exp2f(z0[1]));
            tt[1] = pk2(__builtin_amdgcn_exp2f(z0[2]), __builtin_amdgcn_exp2f(z0[3]));
            f32x4 z1 = cw1;
            z1 = mfma16(xa10, qb[mi][0], z1);
            z1 = mfma16(xa11, qb[mi][1], z1);
            tt[2] = pk2(__builtin_amdgcn_exp2f(z1[0]), __builtin_amdgcn_exp2f(z1[1]));
            tt[3] = pk2(__builtin_amdgcn_exp2f(z1[2]), __builtin_amdgcn_exp2f(z1[3]));
            pa[mi] = __builtin_bit_cast(bf16x8, tt);
            po_sum[mi] = mfma16(pa[mi], onesb, po_sum[mi]);
        }
        #pragma unroll
        for (int nt = 0; nt < 4; ++nt){
            po[0][nt] = mfma16(pa[0], vb[nt], po[0][nt]);
            po[1][nt] = mfma16(pa[1], vb[nt], po[1][nt]);
        }
        __builtin_amdgcn_s_setprio(0);
    }

    __syncthreads();                      // all Xs/VtF frag reads done block-wide
    u16t* OutS = VtF;

    if (!COL){
        // O'[y][c] = out_r + bv + X; OutS [y][c] swizzled (32KB, full slice)
        #pragma unroll
        for (int mi = 0; mi < 2; ++mi){
            const int mt = wv + 8*mi;
            float rs[4];
            #pragma unroll
            for (int r = 0; r < 4; ++r) rs[r] = __builtin_amdgcn_rcpf(po_sum[mi][r]);
            #pragma unroll
            for (int nt = 0; nt < 4; ++nt){
                const int c = nt*16 + l15;
                const float b = bvs[c];
                #pragma unroll
                for (int r01 = 0; r01 < 2; ++r01){
                    float vr[2];
                    #pragma unroll
                    for (int e = 0; e < 2; ++e){
                        const int r = 2*r01 + e;
                        const int y = mt*16 + 4*l4 + r;
                        const float xres = bf2f(*(const u16t*)(Xc + xswz(y, c>>3) + (c&7)*2));
                        vr[e] = po[mi][nt][r]*rs[r] + b + xres;
                    }
                    const int y0 = mt*16 + 4*l4 + 2*r01;
                    const unsigned v = pk2(vr[0], vr[1]);
                    *(u16t*)((char*)OutS + y0*128 + (((c>>3)<<4) ^ ((y0&7)<<4)) + (c&7)*2) = (u16t)v;
                    *(u16t*)((char*)OutS + (y0+1)*128 + (((c>>3)<<4) ^ (((y0+1)&7)<<4)) + (c&7)*2) = (u16t)(v >> 16);
                }
            }
        }
        __syncthreads();
        // write O' w-major: contiguous 32KB block at [n][w=idx][0..256)[c]
        #pragma unroll
        for (int p = 0; p < 4; ++p){
            const int id = p*512 + tid;
            const int y = id >> 3, ch = id & 7;
            us8 v = *(const us8*)((const char*)OutS + y*128 + ((ch<<4) ^ ((y&7)<<4)));
            *(us8*)(Og + sbase + y*64 + ch*8) = v;
        }
    } else {
        // stage O' slice into Xs (linear [w][c]); Xs reads all done at the sync
        #pragma unroll
        for (int p = 0; p < 4; ++p){
            const int id = p*512 + tid;
            const int wl = id >> 3, ch = id & 7;
            us8 v = *(const us8*)(Og + nbase + wl*16384 + idx*64 + ch*8);
            *(us8*)(Xs + id*8) = v;
        }
        __syncthreads();
        // out = out_c + bv + O'; OutS [c][w] swizzled (32KB)
        #pragma unroll
        for (int mi = 0; mi < 2; ++mi){
            const int mt = wv + 8*mi;
            float rs[4];
            #pragma unroll
            for (int r = 0; r < 4; ++r) rs[r] = __builtin_amdgcn_rcpf(po_sum[mi][r]);
            #pragma unroll
            for (int nt = 0; nt < 4; ++nt){
                const int c = nt*16 + l15;
                const float b = bvs[c];
                #pragma unroll
                for (int r01 = 0; r01 < 2; ++r01){
                    float vr[2];
                    #pragma unroll
                    for (int e = 0; e < 2; ++e){
                        const int r = 2*r01 + e;
                        const int wl = mt*16 + 4*l4 + r;
                        vr[e] = po[mi][nt][r]*rs[r] + b + bf2f(Xs[wl*64 + c]);
                    }
                    const int w0 = mt*16 + 4*l4 + 2*r01;
                    *(unsigned*)((char*)OutS + c*512 + ((w0*2) ^ ((c&7)<<4))) = pk2(vr[0], vr[1]);
                }
            }
        }
        __syncthreads();
        // final: out[n][c][idx][:] fp32, coalesced
        const int c = tid >> 3, q = tid & 7;
        const int gb = ((n*64 + c)*256 + idx)*256;
        #pragma unroll
        for (int k = 0; k < 8; ++k){
            const int w0 = q*4 + k*32;
            us4 ov = *(const us4*)((const char*)OutS + c*512 + ((w0*2) ^ ((c&7)<<4)));
            f32x4 res;
            #pragma unroll
            for (int e = 0; e < 4; ++e) res[e] = bf2f(ov[e]);
            *(f32x4*)(outp + gb + w0) = res;
        }
    }
}

extern "C" void kernel_launch(void* const* d_in, const int* in_sizes, int n_in,
                              void* d_out, int out_size, void* d_ws, size_t ws_size,
                              hipStream_t stream){
    const float* h   = (const float*)d_in[0];
    const float* wq  = (const float*)d_in[1];
    const float* bq  = (const float*)d_in[2];
    const float* wk  = (const float*)d_in[3];
    // d_in[4] = bk: cancels in softmax (row-constant), unused.
    const float* wvw = (const float*)d_in[5];
    const float* bv  = (const float*)d_in[6];
    float* out = (float*)d_out;

    u16t* hT = (u16t*)d_ws;               // 128MB (N,H,W,C)
    u16t* Op = hT + 67108864;             // 128MB O' (N,W,H,C)

    transpose_kernel<<<4096, 256, 0, stream>>>(h, hT);
    attn_kernel<0><<<4096, 512, 0, stream>>>(hT, wq, bq, wk, wvw, bv, Op, nullptr);
    attn_kernel<1><<<4096, 512, 0, stream>>>(hT, wq, bq, wk, wvw, bv, Op, out);
}

// Round 19
// 376.893 us; speedup vs baseline: 1.8589x; 1.8589x over previous
//
#include <hip/hip_runtime.h>

// Axial attention for N=16, C=64, H=W=256.  (R19 = exact revert to R16, the
// measured best: 377.3us. R18's software-pipeline + w16s tweaks spilled to
// scratch at the 64-arch-VGPR cap -> WRITE_SIZE 262MB->700MB, 2x regression.)
//
// hT = d_ws[0..128MB):   (N,H,W,C) bf16 pixels (128B each)
// O' = d_ws[128..256MB): (N,W,H,C) bf16  [w-major: attn<0> writes contiguous slices]
//
// K1 transpose_kernel: h (NCHW f32) -> hT (N,H,W,C bf16)
// K2 attn<0> (row):  per (n,w): X = hT[:, :, w, :]; O' = out_r + bv + X (full slice)
// K3 attn<1> (col):  per (n,y): X = hT[n][y] (contig); O' staged via LDS;
//                    out = out_c + bv + O' (fp32 NCHW, coalesced)
//
// softmax(q.k^T) == softmax( X*(At/16)*X^T + w[g]/16 ), At^T = Wk^T Wq as A-operand;
// w[g] = X[g].(Wk^T bq); query-bias terms cancel; bk cancels. V bias in epilogue.
// No max-sub (scores bounded, fp32 exp safe); log2e folded into At/w16s.

typedef unsigned short u16t;
typedef __bf16 bf16x8 __attribute__((ext_vector_type(8)));
typedef __bf16 bf16x2 __attribute__((ext_vector_type(2)));
typedef float  f32x4  __attribute__((ext_vector_type(4)));
typedef u16t   us8    __attribute__((ext_vector_type(8)));
typedef u16t   us4    __attribute__((ext_vector_type(4)));
typedef unsigned uu4  __attribute__((ext_vector_type(4)));

#define DEVINL __device__ __forceinline__

#define SCL16 0.09016844f   // log2(e)/16

DEVINL u16t f2bf(float f){
    return __builtin_bit_cast(u16t, (__bf16)f);      // hw cvt (RNE)
}
DEVINL float bf2f(u16t h){
    unsigned u = ((unsigned)h) << 16;
    return __builtin_bit_cast(float, u);
}
DEVINL unsigned pk2(float lo, float hi){
    bf16x2 t; t[0] = (__bf16)lo; t[1] = (__bf16)hi;  // canonical v_cvt_pk pattern
    return __builtin_bit_cast(unsigned, t);
}
DEVINL f32x4 mfma16(bf16x8 a, bf16x8 b, f32x4 c){
    return __builtin_amdgcn_mfma_f32_16x16x32_bf16(a, b, c, 0, 0, 0);
}
// Xs swizzle (reference form; hot loops use hoisted equivalents)
DEVINL int xswz(int row, int chunk){
    return row*128 + ((chunk << 4) ^ (((row & 7) ^ ((row >> 2) & 7)) << 4));
}

// ---------------- K1: transpose h (N,C,H,W) f32 -> hT (N,H,W,C) bf16 ----------------
__global__ __launch_bounds__(256) void transpose_kernel(const float* __restrict__ h,
                                                        u16t* __restrict__ hT){
    __shared__ float tile[64][257];
    const int bid = blockIdx.x;          // n*256 + y
    const int n = bid >> 8, y = bid & 255;
    const int tid = threadIdx.x;
    {
        const int c = tid >> 2, w0 = (tid & 3) * 64;
        const int base = ((n * 64 + c) * 256 + y) * 256 + w0;
        #pragma unroll
        for (int i = 0; i < 16; ++i){
            f32x4 v = *(const f32x4*)(h + base + i * 4);
            tile[c][w0 + i*4 + 0] = v[0];
            tile[c][w0 + i*4 + 1] = v[1];
            tile[c][w0 + i*4 + 2] = v[2];
            tile[c][w0 + i*4 + 3] = v[3];
        }
    }
    __syncthreads();
    #pragma unroll
    for (int j = 0; j < 4; ++j){
        const int task = tid + 256 * j;
        const int w = task >> 2, c0 = (task & 3) * 16;
        us8 o0, o1;
        #pragma unroll
        for (int e = 0; e < 8; ++e) o0[e] = f2bf(tile[c0 + e][w]);
        #pragma unroll
        for (int e = 0; e < 8; ++e) o1[e] = f2bf(tile[c0 + 8 + e][w]);
        const int ob = ((n * 256 + y) * 256 + w) * 64 + c0;
        *(us8*)(hT + ob)     = o0;
        *(us8*)(hT + ob + 8) = o1;
    }
}

// ---------------- K2/K3: attention (full-slice blocks, 2 q-tiles per wave) ----------------
template<int COL>
__global__ __launch_bounds__(512, 4) void attn_kernel(
    const u16t* __restrict__ Xg,
    const float* __restrict__ wq, const float* __restrict__ bq,
    const float* __restrict__ wk, const float* __restrict__ wvw,
    const float* __restrict__ bvp,
    u16t* __restrict__ Og,
    float* __restrict__ outp)
{
    __shared__ __align__(16) u16t Xs[16384];    // X 256x64 bf16 swizzled; COL: later O' stage
    __shared__ __align__(16) u16t VtF[16384];   // V as PV B-frags (linear); reused as OutS
    __shared__ __align__(16) u16t AtF[4096];    // At^T*log2e/16 as A-frags (virtual perm)
    __shared__ __align__(16) float w16s[256];
    __shared__ float wkbqs[64];
    __shared__ float bvs[64];

    const int tid  = threadIdx.x;
    const int lane = tid & 63;
    const int wv   = tid >> 6;                 // wave 0..7
    const int bid  = blockIdx.x;               // grid = 4096
    const int n    = bid >> 8;
    const int idx  = bid & 255;                // w (row mode) or y (col mode)
    const int l15  = lane & 15;
    const int l4   = lane >> 4;
    const int nbase = n * 4194304;
    const int sbase = nbase + idx * 16384;
    const int aa   = l15 >> 2, bb = l15 & 3;
    const char* Xc = (const char*)Xs;

    // ---- phase 0a: stage full X into LDS (hoisted pass-invariant swizzle)
    {
        const int r0 = tid >> 3, cc = tid & 7;
        const int swzS = (((r0 & 7) ^ ((tid >> 5) & 7)) << 4);
        char* pdst = (char*)Xs + r0*128 + ((cc << 4) ^ swzS);
        const u16t* psrc = Xg + (COL ? (sbase + r0*64 + cc*8)
                                     : (nbase + r0*16384 + idx*64 + cc*8));
        const int gstep = COL ? 4096 : 1048576;   // 64 rows per pass
        #pragma unroll
        for (int pass = 0; pass < 4; ++pass){
            us8 v = *(const us8*)(psrc + pass*gstep);
            *(us8*)(pdst + pass*8192) = v;
        }
    }

    // ---- phase 0b: At^T*log2e/16 -> AtF (A-frag layout, virtual-row perm)
    {
        const int mtA = wv >> 1;
        us8 aku[2];
        #pragma unroll
        for (int kt = 0; kt < 2; ++kt)
            #pragma unroll
            for (int e = 0; e < 8; ++e)
                aku[kt][e] = f2bf(wk[(kt*32 + l4*8 + e)*64 + mtA*16 + l15]);
        #pragma unroll
        for (int t2 = 0; t2 < 2; ++t2){
            const int ntA = (2*wv + t2) & 3;
            us8 bqu[2];
            #pragma unroll
            for (int kt = 0; kt < 2; ++kt)
                #pragma unroll
                for (int e = 0; e < 8; ++e)
                    bqu[kt][e] = f2bf(wq[(kt*32 + l4*8 + e)*64 + ntA*16 + l15]);
            f32x4 acc = {0.f,0.f,0.f,0.f};
            acc = mfma16(__builtin_bit_cast(bf16x8, aku[0]), __builtin_bit_cast(bf16x8, bqu[0]), acc);
            acc = mfma16(__builtin_bit_cast(bf16x8, aku[1]), __builtin_bit_cast(bf16x8, bqu[1]), acc);
            #pragma unroll
            for (int r = 0; r < 4; ++r){
                const int cp = mtA*16 + 4*l4 + r;          // row of At^T (= c')
                const int cc = ntA*16 + l15;               // col (= c, the k-dim)
                const int vtq  = 2*(cp>>5) + ((cp>>2)&1);
                const int mrow = 4*((cp>>3)&3) + (cp&3);
                const int f    = vtq*2 + (cc>>5);
                AtF[(f*64 + ((cc>>3)&3)*16 + mrow)*8 + (cc&7)] = f2bf(acc[r] * SCL16);
            }
        }
    }
    if (tid < 64){
        float acc = 0.f;
        for (int o = 0; o < 64; ++o) acc += wk[o*64 + tid] * bq[o];
        wkbqs[tid] = acc;
        bvs[tid] = bvp[tid];
    }
    __syncthreads();

    // ---- phase 1: V = X @ Wv^T -> PV B-frag layout (hoisted addresses)
    {
        const int ct = wv >> 1;
        bf16x8 awv[2];
        #pragma unroll
        for (int ktc = 0; ktc < 2; ++ktc){
            const float* wp = wvw + (ct*16 + l15)*64 + ktc*32 + l4*8;
            f32x4 v0 = *(const f32x4*)wp;
            f32x4 v1 = *(const f32x4*)(wp + 4);
            us8 u;
            #pragma unroll
            for (int e = 0; e < 4; ++e){ u[e] = f2bf(v0[e]); u[4+e] = f2bf(v1[e]); }
            awv[ktc] = __builtin_bit_cast(bf16x8, u);
        }
        // read bases: row = gt*16 + l15, gt = (wv&1)*8 + t; parity constants
        const char* pb0 = Xc + (wv&1)*16384 + l15*128;
        const int swzE = (((l15&7) ^ aa) << 4);
        const int swzO = (((l15&7) ^ (4+aa)) << 4);
        const int cE0 = (l4<<4) ^ swzE, cE1 = ((4+l4)<<4) ^ swzE;
        const int cO0 = (l4<<4) ^ swzO, cO1 = ((4+l4)<<4) ^ swzO;
        // write base: VtF[(fidx*64 + lt + rr)*8 + e] bytes
        char* pvw = (char*)VtF + (ct*8 + (wv&1)*4)*1024 + (l15>>3)*256 + l4*64 + (l15&7)*2;
        #pragma unroll
        for (int t = 0; t < 8; ++t){
            const int o0 = (t&1) ? cO0 : cE0, o1 = (t&1) ? cO1 : cE1;
            bf16x8 bx0 = *(const bf16x8*)(pb0 + t*2048 + o0);
            bf16x8 bx1 = *(const bf16x8*)(pb0 + t*2048 + o1);
            f32x4 z = {0.f,0.f,0.f,0.f};
            z = mfma16(awv[0], bx0, z);
            z = mfma16(awv[1], bx1, z);
            char* pw8 = pvw + (t>>1)*1024 + (t&1)*512;
            #pragma unroll
            for (int rr = 0; rr < 4; ++rr)
                *(u16t*)(pw8 + rr*16) = f2bf(z[rr]);
        }
    }
    if (tid < 256){
        float acc = 0.f;
        #pragma unroll
        for (int cc = 0; cc < 8; ++cc){
            us8 xv = *(const us8*)(Xc + xswz(tid, cc));
            #pragma unroll
            for (int e = 0; e < 8; ++e) acc += bf2f(xv[e]) * wkbqs[cc*8 + e];
        }
        w16s[tid] = acc * SCL16;
    }
    __syncthreads();

    // ---- phase 2: TWO q-tiles per wave (mt = wv, wv+8), flash-fused, reads shared
    const int rowoff = 8*aa + bb;

    // q~ for both tiles; AtF frags read once, shared across mi
    const char* pat = (const char*)AtF + lane*16;
    bf16x8 xq[2][2];
    #pragma unroll
    for (int mi = 0; mi < 2; ++mi){
        const int mt = wv + 8*mi;
        xq[mi][0] = *(const bf16x8*)(Xc + xswz(mt*16 + l15, l4));
        xq[mi][1] = *(const bf16x8*)(Xc + xswz(mt*16 + l15, 4 + l4));
    }
    uu4 qp[2][2];
    #pragma unroll
    for (int vtq = 0; vtq < 4; ++vtq){
        bf16x8 a0 = *(const bf16x8*)(pat + (vtq*2 + 0)*1024);
        bf16x8 a1 = *(const bf16x8*)(pat + (vtq*2 + 1)*1024);
        #pragma unroll
        for (int mi = 0; mi < 2; ++mi){
            f32x4 z = {0.f,0.f,0.f,0.f};
            z = mfma16(a0, xq[mi][0], z);
            z = mfma16(a1, xq[mi][1], z);
            qp[mi][vtq>>1][(vtq&1)*2 + 0] = pk2(z[0], z[1]);
            qp[mi][vtq>>1][(vtq&1)*2 + 1] = pk2(z[2], z[3]);
        }
    }
    bf16x8 qb[2][2];
    qb[0][0] = __builtin_bit_cast(bf16x8, qp[0][0]);
    qb[0][1] = __builtin_bit_cast(bf16x8, qp[0][1]);
    qb[1][0] = __builtin_bit_cast(bf16x8, qp[1][0]);
    qb[1][1] = __builtin_bit_cast(bf16x8, qp[1][1]);

    // hoisted virtual-read bases: row = 32kt + 4sub + rowoff (disjoint bitfields)
    const int swz0 = (bb ^ (2*aa)) << 4;
    const int swz1 = ((4 + bb) ^ ((2*aa + 1) & 7)) << 4;
    const char* pv00 = Xc + rowoff*128 + ((l4<<4) ^ swz0);
    const char* pv01 = Xc + rowoff*128 + (((4+l4)<<4) ^ swz0);
    const char* pv10 = Xc + rowoff*128 + 512 + ((l4<<4) ^ swz1);
    const char* pv11 = Xc + rowoff*128 + 512 + (((4+l4)<<4) ^ swz1);
    const char* pvv = (const char*)VtF + lane*16;   // linear, conflict-free
    const char* pw  = (const char*)w16s + l4*32;

    // ones B-frag for row-sum MFMA
    uu4 onep; onep[0] = 0x3F803F80u; onep[1] = 0x3F803F80u; onep[2] = 0x3F803F80u; onep[3] = 0x3F803F80u;
    const bf16x8 onesb = __builtin_bit_cast(bf16x8, onep);

    f32x4 po[2][4] = {{{0.f,0.f,0.f,0.f},{0.f,0.f,0.f,0.f},{0.f,0.f,0.f,0.f},{0.f,0.f,0.f,0.f}},
                      {{0.f,0.f,0.f,0.f},{0.f,0.f,0.f,0.f},{0.f,0.f,0.f,0.f},{0.f,0.f,0.f,0.f}}};
    f32x4 po_sum[2] = {{0.f,0.f,0.f,0.f},{0.f,0.f,0.f,0.f}};

    #pragma unroll
    for (int kt = 0; kt < 8; ++kt){
        // ALL LDS reads for this kt issued up front: xa(4) + cw(2) + vb(4).
        bf16x8 xa00 = *(const bf16x8*)(pv00 + kt*4096);
        bf16x8 xa01 = *(const bf16x8*)(pv01 + kt*4096);
        bf16x8 xa10 = *(const bf16x8*)(pv10 + kt*4096);
        bf16x8 xa11 = *(const bf16x8*)(pv11 + kt*4096);
        f32x4 cw0 = *(const f32x4*)(pw + kt*128);
        f32x4 cw1 = *(const f32x4*)(pw + kt*128 + 16);
        bf16x8 vb[4];
        #pragma unroll
        for (int nt = 0; nt < 4; ++nt)
            vb[nt] = *(const bf16x8*)(pvv + (nt*8 + kt)*1024);

        __builtin_amdgcn_s_setprio(1);
        bf16x8 pa[2];
        #pragma unroll
        for (int mi = 0; mi < 2; ++mi){
            uu4 tt;
            f32x4 z0 = cw0;
            z0 = mfma16(xa00, qb[mi][0], z0);
            z0 = mfma16(xa01, qb[mi][1], z0);
            tt[0] = pk2(__builtin_amdgcn_exp2f(z0[0]), __builtin_amdgcn_exp2f(z0[1]));
            tt[1] = pk2(__builtin_amdgcn_exp2f(z0[2]), __builtin_amdgcn_exp2f(z0[3]));
            f32x4 z1 = cw1;
            z1 = mfma16(xa10, qb[mi][0], z1);
            z1 = mfma16(xa11, qb[mi][1], z1);
            tt[2] = pk2(__builtin_amdgcn_exp2f(z1[0]), __builtin_amdgcn_exp2f(z1[1]));
            tt[3] = pk2(__builtin_amdgcn_exp2f(z1[2]), __builtin_amdgcn_exp2f(z1[3]));
            pa[mi] = __builtin_bit_cast(bf16x8, tt);
            po_sum[mi] = mfma16(pa[mi], onesb, po_sum[mi]);
        }
        #pragma unroll
        for (int nt = 0; nt < 4; ++nt){
            po[0][nt] = mfma16(pa[0], vb[nt], po[0][nt]);
            po[1][nt] = mfma16(pa[1], vb[nt], po[1][nt]);
        }
        __builtin_amdgcn_s_setprio(0);
    }

    __syncthreads();                      // all Xs/VtF frag reads done block-wide
    u16t* OutS = VtF;

    if (!COL){
        // O'[y][c] = out_r + bv + X; OutS [y][c] swizzled (32KB, full slice)
        #pragma unroll
        for (int mi = 0; mi < 2; ++mi){
            const int mt = wv + 8*mi;
            float rs[4];
            #pragma unroll
            for (int r = 0; r < 4; ++r) rs[r] = __builtin_amdgcn_rcpf(po_sum[mi][r]);
            #pragma unroll
            for (int nt = 0; nt < 4; ++nt){
                const int c = nt*16 + l15;
                const float b = bvs[c];
                #pragma unroll
                for (int r01 = 0; r01 < 2; ++r01){
                    float vr[2];
                    #pragma unroll
                    for (int e = 0; e < 2; ++e){
                        const int r = 2*r01 + e;
                        const int y = mt*16 + 4*l4 + r;
                        const float xres = bf2f(*(const u16t*)(Xc + xswz(y, c>>3) + (c&7)*2));
                        vr[e] = po[mi][nt][r]*rs[r] + b + xres;
                    }
                    const int y0 = mt*16 + 4*l4 + 2*r01;
                    const unsigned v = pk2(vr[0], vr[1]);
                    *(u16t*)((char*)OutS + y0*128 + (((c>>3)<<4) ^ ((y0&7)<<4)) + (c&7)*2) = (u16t)v;
                    *(u16t*)((char*)OutS + (y0+1)*128 + (((c>>3)<<4) ^ (((y0+1)&7)<<4)) + (c&7)*2) = (u16t)(v >> 16);
                }
            }
        }
        __syncthreads();
        // write O' w-major: contiguous 32KB block at [n][w=idx][0..256)[c]
        #pragma unroll
        for (int p = 0; p < 4; ++p){
            const int id = p*512 + tid;
            const int y = id >> 3, ch = id & 7;
            us8 v = *(const us8*)((const char*)OutS + y*128 + ((ch<<4) ^ ((y&7)<<4)));
            *(us8*)(Og + sbase + y*64 + ch*8) = v;
        }
    } else {
        // stage O' slice into Xs (linear [w][c]); Xs reads all done at the sync
        #pragma unroll
        for (int p = 0; p < 4; ++p){
            const int id = p*512 + tid;
            const int wl = id >> 3, ch = id & 7;
            us8 v = *(const us8*)(Og + nbase + wl*16384 + idx*64 + ch*8);
            *(us8*)(Xs + id*8) = v;
        }
        __syncthreads();
        // out = out_c + bv + O'; OutS [c][w] swizzled (32KB)
        #pragma unroll
        for (int mi = 0; mi < 2; ++mi){
            const int mt = wv + 8*mi;
            float rs[4];
            #pragma unroll
            for (int r = 0; r < 4; ++r) rs[r] = __builtin_amdgcn_rcpf(po_sum[mi][r]);
            #pragma unroll
            for (int nt = 0; nt < 4; ++nt){
                const int c = nt*16 + l15;
                const float b = bvs[c];
                #pragma unroll
                for (int r01 = 0; r01 < 2; ++r01){
                    float vr[2];
                    #pragma unroll
                    for (int e = 0; e < 2; ++e){
                        const int r = 2*r01 + e;
                        const int wl = mt*16 + 4*l4 + r;
                        vr[e] = po[mi][nt][r]*rs[r] + b + bf2f(Xs[wl*64 + c]);
                    }
                    const int w0 = mt*16 + 4*l4 + 2*r01;
                    *(unsigned*)((char*)OutS + c*512 + ((w0*2) ^ ((c&7)<<4))) = pk2(vr[0], vr[1]);
                }
            }
        }
        __syncthreads();
        // final: out[n][c][idx][:] fp32, coalesced
        const int c = tid >> 3, q = tid & 7;
        const int gb = ((n*64 + c)*256 + idx)*256;
        #pragma unroll
        for (int k = 0; k < 8; ++k){
            const int w0 = q*4 + k*32;
            us4 ov = *(const us4*)((const char*)OutS + c*512 + ((w0*2) ^ ((c&7)<<4)));
            f32x4 res;
            #pragma unroll
            for (int e = 0; e < 4; ++e) res[e] = bf2f(ov[e]);
            *(f32x4*)(outp + gb + w0) = res;
        }
    }
}

extern "C" void kernel_launch(void* const* d_in, const int* in_sizes, int n_in,
                              void* d_out, int out_size, void* d_ws, size_t ws_size,
                              hipStream_t stream){
    const float* h   = (const float*)d_in[0];
    const float* wq  = (const float*)d_in[1];
    const float* bq  = (const float*)d_in[2];
    const float* wk  = (const float*)d_in[3];
    // d_in[4] = bk: cancels in softmax (row-constant), unused.
    const float* wvw = (const float*)d_in[5];
    const float* bv  = (const float*)d_in[6];
    float* out = (float*)d_out;

    u16t* hT = (u16t*)d_ws;               // 128MB (N,H,W,C)
    u16t* Op = hT + 67108864;             // 128MB O' (N,W,H,C)

    transpose_kernel<<<4096, 256, 0, stream>>>(h, hT);
    attn_kernel<0><<<4096, 512, 0, stream>>>(hT, wq, bq, wk, wvw, bv, Op, nullptr);
    attn_kernel<1><<<4096, 512, 0, stream>>>(hT, wq, bq, wk, wvw, bv, Op, out);
}